// Round 5
// baseline (10.730 us; speedup 1.0000x reference)
//
#include <hip/hip_runtime.h>
#include <hip/hip_bf16.h>

// ---------------------------------------------------------------------------
// Fully fused VQC kernel, v3.
//
// out = psi^T M psi,  psi = separable real encoded state (3 angles from x),
// M = Re(U^dag Z0 U) with U the batch-uniform variational 8x8 unitary.
//
// v3 changes vs v2:
//  - All 18 sincos of the M-build hoisted upfront (independent -> pipelined);
//    v2 serialized each sincos into the dependent gate chain.
//  - 4 rows per thread (512 blocks): half the redundant M-builds, 64 B of
//    sequential float4 loads per thread, float4 coalesced store.
// ---------------------------------------------------------------------------
__global__ __launch_bounds__(256) void vqc_fused(const float* __restrict__ x,
                                                 const float* __restrict__ w,
                                                 float* __restrict__ out,
                                                 int B4 /* = B/4 */) {
    __shared__ float sUr[8][8], sUi[8][8];  // [k][column]
    __shared__ float sM[64];

    const int tid = threadIdx.x;

    // ---- per-block M build (wave 0, lanes 0-7; redundant across blocks) ---
    if (tid < 8) {
        // 18 independent sincos first (pipelined, not on the gate chain).
        float ryc[9], rys[9], rzc[9], rzs[9];
#pragma unroll
        for (int g = 0; g < 9; ++g) {
            __sincosf(0.5f * w[2 * g + 0], &rys[g], &ryc[g]);
            __sincosf(0.5f * w[2 * g + 1], &rzs[g], &rzc[g]);
        }

        float ar[8], ai[8];
#pragma unroll
        for (int k = 0; k < 8; ++k) {
            ar[k] = (k == tid) ? 1.0f : 0.0f;
            ai[k] = 0.0f;
        }

#pragma unroll
        for (int l = 0; l < 3; ++l) {
#pragma unroll
            for (int i = 0; i < 3; ++i) {
                const int g = l * 3 + i;
                const int m = 1 << (2 - i);          // bit mask of qubit i

                // RY on qubit i
                const float c = ryc[g], s = rys[g];
#pragma unroll
                for (int k = 0; k < 8; ++k) {
                    if (k & m) continue;
                    const float a0r = ar[k],     a0i = ai[k];
                    const float a1r = ar[k | m], a1i = ai[k | m];
                    ar[k]     = c * a0r - s * a1r;  ai[k]     = c * a0i - s * a1i;
                    ar[k | m] = s * a0r + c * a1r;  ai[k | m] = s * a0i + c * a1i;
                }

                // RZ on qubit i
                const float cz = rzc[g], sz = rzs[g];
#pragma unroll
                for (int k = 0; k < 8; ++k) {
                    const float pi = (k & m) ? sz : -sz;
                    const float r  = ar[k] * cz - ai[k] * pi;
                    const float q  = ar[k] * pi + ai[k] * cz;
                    ar[k] = r; ai[k] = q;
                }
            }
            // CNOT(0,1): swap 4<->6, 5<->7
#pragma unroll
            for (int k = 4; k <= 5; ++k) {
                const int k2 = k | 2;
                float tr = ar[k]; ar[k] = ar[k2]; ar[k2] = tr;
                float ti = ai[k]; ai[k] = ai[k2]; ai[k2] = ti;
            }
            // CNOT(1,2): swap 2<->3, 6<->7
#pragma unroll
            for (int k = 2; k <= 6; k += 4) {
                const int k2 = k | 1;
                float tr = ar[k]; ar[k] = ar[k2]; ar[k2] = tr;
                float ti = ai[k]; ai[k] = ai[k2]; ai[k2] = ti;
            }
        }

#pragma unroll
        for (int k = 0; k < 8; ++k) { sUr[k][tid] = ar[k]; sUi[k][tid] = ai[k]; }
    }
    __syncthreads();

    if (tid < 64) {
        const int a = tid >> 3, b = tid & 7;
        float acc = 0.f;
#pragma unroll
        for (int k = 0; k < 8; ++k) {
            const float z = (k < 4) ? 1.f : -1.f;
            acc += z * (sUr[k][a] * sUr[k][b] + sUi[k][a] * sUi[k][b]);
        }
        sM[tid] = acc;
    }
    __syncthreads();

    // Each lane holds one M element; m_ij comes from v_readlane (SGPR).
    const float mv = sM[tid & 63];

    // ---- streaming phase: 4 rows per thread -------------------------------
    const int t = blockIdx.x * blockDim.x + tid;   // t in [0, B/4)
    if (t >= B4) return;

    const float* xp = x + (size_t)t * 32;          // 4 rows x 32 B
    float4 xr[4];
#pragma unroll
    for (int r = 0; r < 4; ++r)
        xr[r] = *reinterpret_cast<const float4*>(xp + r * 8);

    float psi[4][8];
#pragma unroll
    for (int r = 0; r < 4; ++r) {
        float s0, c0, s1, c1, s2, c2;
        __sincosf(0.5f * xr[r].x, &s0, &c0);
        __sincosf(0.5f * xr[r].y, &s1, &c1);
        __sincosf(0.5f * xr[r].z, &s2, &c2);
        const float t0[2] = {c0, s0}, t1[2] = {c1, s1}, t2[2] = {c2, s2};
#pragma unroll
        for (int k = 0; k < 8; ++k)
            psi[r][k] = t0[(k >> 2) & 1] * t1[(k >> 1) & 1] * t2[k & 1];
    }

    float acc[4] = {0.f, 0.f, 0.f, 0.f};
#pragma unroll
    for (int i = 0; i < 8; ++i) {
        float rr[4] = {0.f, 0.f, 0.f, 0.f};
#pragma unroll
        for (int j = 0; j < 8; ++j) {
            const float mij = __int_as_float(
                __builtin_amdgcn_readlane(__float_as_int(mv), i * 8 + j));
#pragma unroll
            for (int r = 0; r < 4; ++r)
                rr[r] = fmaf(mij, psi[r][j], rr[r]);
        }
#pragma unroll
        for (int r = 0; r < 4; ++r)
            acc[r] = fmaf(psi[r][i], rr[r], acc[r]);
    }

    *reinterpret_cast<float4*>(out + (size_t)t * 4) =
        make_float4(acc[0], acc[1], acc[2], acc[3]);
}

// ---------------------------------------------------------------------------
extern "C" void kernel_launch(void* const* d_in, const int* in_sizes, int n_in,
                              void* d_out, int out_size, void* d_ws, size_t ws_size,
                              hipStream_t stream) {
    const float* x = (const float*)d_in[0];   // [B, 8] f32
    const float* w = (const float*)d_in[1];   // [3, 3, 2] f32
    float* out = (float*)d_out;               // [B, 1] f32

    const int B = out_size;                   // 524288 (divisible by 1024)
    const int B4 = B / 4;

    vqc_fused<<<(B4 + 255) / 256, 256, 0, stream>>>(x, w, out, B4);
}